// Round 15
// baseline (225.620 us; speedup 1.0000x reference)
//
#include <hip/hip_runtime.h>

// TripletAngularMarginLoss: bs=16384, d=64 (== number of classes)
// out = mean(relu(0.5 + ap - an)) + mean(relu(0.8-ap)) + mean(relu(an-0.4)) + CE
// ap[i] = min_{t[j]==t[i]} cos(x_i,x_j), an[i] = max_{t[j]!=t[i]} cos(x_i,x_j)
//
// R13 ledger: mine is 101-107us for every non-spilling variant (R1/4/7/8/9);
// barriers, counted-vmcnt, occupancy, sort, and ILP levers all null or
// regressive; ILP attempts (R6/R13) explode into spill at the allocator's
// fixed arch-VGPR grant. R14 banks the mechanical wins instead:
//  - finalize folded into mine's last block (done-counter, verified R11/R12)
//  - prep: max-pass removed (|xn|<=1 -> exp in [0.37,2.72], sum<=174, safe)
//  - mine compute loop byte-identical to R7 (best verified variant)
// 2 launches total (was 3 + finalize).

#define N_ROWS 16384
#define N_DIM 64

typedef __attribute__((ext_vector_type(8))) short bf16x8;
typedef __attribute__((ext_vector_type(4))) float f32x4;

__device__ inline unsigned short f2bf(float f) {
  unsigned u = __float_as_uint(f);
  unsigned r = u + 0x7fffu + ((u >> 16) & 1u);   // round-to-nearest-even
  return (unsigned short)(r >> 16);
}

// order-preserving float->uint encoding for atomicMin/atomicMax
__device__ inline unsigned enc_key(float f) {
  unsigned u = __float_as_uint(f);
  return (u & 0x80000000u) ? ~u : (u | 0x80000000u);
}
__device__ inline float dec_key(unsigned k) {
  unsigned u = (k & 0x80000000u) ? (k ^ 0x80000000u) : ~k;
  return __uint_as_float(u);
}

// async global->LDS DMA, 16B per lane, dest = lds_base + lane*16 (linear)
__device__ inline void g2lds16(const void* g, void* l) {
  __builtin_amdgcn_global_load_lds(
      (const __attribute__((address_space(1))) void*)g,
      (__attribute__((address_space(3))) void*)l, 16, 0, 0);
}

// ---------------- Kernel A: normalize rows, emit bf16 copy, per-row CE -------
// No max-pass: xn is L2-normalized (|xn|<=1) so exp(xn) in [0.37,2.72] and the
// 64-term sum <= 174 -- f32-safe; lse = log(sum(exp(xn))) directly.
__global__ void prep_kernel(const float* __restrict__ x, const int* __restrict__ tgt,
                            unsigned short* __restrict__ xb, float* __restrict__ ce_row,
                            unsigned* __restrict__ mp_key, unsigned* __restrict__ mn_key) {
  const int row  = blockIdx.x * 4 + (threadIdx.x >> 6);
  const int lane = threadIdx.x & 63;
  float v  = x[row * N_DIM + lane];
  float ss = v * v;
#pragma unroll
  for (int s = 1; s < 64; s <<= 1) ss += __shfl_xor(ss, s, 64);
  float xn = v * rsqrtf(ss);
  xb[row * N_DIM + lane] = f2bf(xn);

  float e  = __expf(xn);
  float se = e;
#pragma unroll
  for (int s = 1; s < 64; s <<= 1) se += __shfl_xor(se, s, 64);
  float lse = __logf(se);
  int   t   = tgt[row];                 // wave-uniform
  float xt  = __shfl(xn, t, 64);
  if (lane == 0) {
    ce_row[row] = lse - xt;
    mp_key[row] = 0xFFFFFFFFu;          // +inf key for atomicMin
    mn_key[row] = 0u;                   // -inf key for atomicMax
  }
}

// ---------------- Kernel B: MFMA similarity + mining + last-block finalize ---
// grid = 128 i-blocks * 16 j-splits = 2048 blocks of 256 threads (4 waves) =
// 8 blocks/CU. Compute loop byte-identical to R7 (best verified: 106us):
// 4-tile phases, dbuf, XOR-swizzle, unroll-1 j4, one syncthreads per phase.
// Tail: done-counter elects the last block to reduce the loss (R11 pattern).
__global__ __launch_bounds__(256, 8)
void mine_kernel(const unsigned short* __restrict__ xb, const int* __restrict__ tgt,
                 unsigned* __restrict__ mp_key, unsigned* __restrict__ mn_key,
                 const float* __restrict__ ce_row, const unsigned* __restrict__ pz,
                 unsigned* __restrict__ done, float* __restrict__ out) {
  __shared__ unsigned short Bt[2][4][1024];   // 2 bufs x 4 tiles x 2KB, swizzled
  __shared__ unsigned short tjl[N_ROWS / 16]; // 2KB: targets of this j-range
  __shared__ float red[4];
  __shared__ bool  last;

  const int lane    = threadIdx.x & 63;
  const int wv      = threadIdx.x >> 6;
  const int iblk    = blockIdx.x >> 4;
  const int jspl    = blockIdx.x & 15;
  const int rowbase = iblk * 128 + wv * 32;
  const int m = lane & 15, q = lane >> 4;
  const int jbase = jspl * (N_ROWS / 16);

  // A fragments: lane holds row (rowbase+tr*16+m), k = q*8..q*8+7 (+32 for ks=1)
  bf16x8 a[2][2];
#pragma unroll
  for (int tr = 0; tr < 2; ++tr) {
    const unsigned short* p = xb + (rowbase + tr * 16 + m) * N_DIM + q * 8;
    a[tr][0] = *(const bf16x8*)(p);
    a[tr][1] = *(const bf16x8*)(p + 32);
  }
  int ti[2][4];
#pragma unroll
  for (int tr = 0; tr < 2; ++tr)
#pragma unroll
    for (int r = 0; r < 4; ++r)
      ti[tr][r] = tgt[rowbase + tr * 16 + q * 4 + r];

  float mp[8], mn[8];
#pragma unroll
  for (int k = 0; k < 8; ++k) { mp[k] = __builtin_inff(); mn[k] = -__builtin_inff(); }

  for (int k = threadIdx.x; k < N_ROWS / 16; k += 256)
    tjl[k] = (unsigned short)tgt[jbase + k];

  // Staging (inverse-swizzled global source, linear LDS dest):
  const unsigned short* src0 =
      xb + (jbase + (lane >> 3)) * N_DIM + (((lane & 7) ^ ((lane >> 3) & 7)) * 8);

#define STAGE(P_, BUF)                                                           \
  do {                                                                           \
    const unsigned short* s_ = src0 + ((P_) * 64 + wv * 16) * N_DIM;             \
    g2lds16(s_,             (unsigned short*)&Bt[(BUF)][wv][0] + lane * 8);      \
    g2lds16(s_ + 8 * N_DIM, (unsigned short*)&Bt[(BUF)][wv][0] + 512 + lane * 8);\
  } while (0)

  STAGE(0, 0);
  __syncthreads();

  // swizzled fragment-read byte offsets (constant per lane)
  const int roff0 = m * 128 + ((q * 16) ^ ((m & 7) << 4));
  const int roff1 = m * 128 + (((64) + q * 16) ^ ((m & 7) << 4));

  for (int ph = 0; ph < 16; ++ph) {
    const int pb = ph & 1;
    if (ph < 15) STAGE(ph + 1, pb ^ 1);
#pragma unroll 1
    for (int j4 = 0; j4 < 4; ++j4) {
      const int jc = ph * 4 + j4;
      const char* bb = (const char*)&Bt[pb][j4][0];
      const bf16x8 cb0 = *(const bf16x8*)(bb + roff0);
      const bf16x8 cb1 = *(const bf16x8*)(bb + roff1);
      const int    ctj = tjl[jc * 16 + m];

#pragma unroll
      for (int tr = 0; tr < 2; ++tr) {
        f32x4 acc = {0.f, 0.f, 0.f, 0.f};
        acc = __builtin_amdgcn_mfma_f32_16x16x32_bf16(a[tr][0], cb0, acc, 0, 0, 0);
        acc = __builtin_amdgcn_mfma_f32_16x16x32_bf16(a[tr][1], cb1, acc, 0, 0, 0);
#pragma unroll
        for (int r = 0; r < 4; ++r) {
          const bool  pos = (ctj == ti[tr][r]);
          const float d   = acc[r];
          const int   k   = tr * 4 + r;
          mp[k] = fminf(mp[k], pos ? d : __builtin_inff());
          mn[k] = fmaxf(mn[k], pos ? -__builtin_inff() : d);
        }
      }
    }
    __syncthreads();   // one vmcnt-drain + barrier per 4-tile phase
  }
#undef STAGE

  // reduce across the 16 lanes (m = 0..15) inside each q-group
#pragma unroll
  for (int s = 1; s < 16; s <<= 1) {
#pragma unroll
    for (int k = 0; k < 8; ++k) {
      mp[k] = fminf(mp[k], __shfl_xor(mp[k], s, 64));
      mn[k] = fmaxf(mn[k], __shfl_xor(mn[k], s, 64));
    }
  }
  if (m == 0) {
#pragma unroll
    for (int tr = 0; tr < 2; ++tr)
#pragma unroll
      for (int r = 0; r < 4; ++r) {
        const int row = rowbase + tr * 16 + q * 4 + r;
        atomicMin(&mp_key[row], enc_key(mp[tr * 4 + r]));
        atomicMax(&mn_key[row], enc_key(mn[tr * 4 + r]));
      }
  }

  // ---- last-block finalize (verified R11/R12): saves a kernel + a gap ----
  __syncthreads();                       // drains this block's atomics (vmcnt)
  if (threadIdx.x == 0) {
    __threadfence();
    unsigned old = atomicAdd(done, 1u);
    last = (old == pz[0] + (unsigned)gridDim.x - 1u);
  }
  __syncthreads();
  if (!last) return;

  float s = 0.f;
  for (int i = threadIdx.x; i < N_ROWS; i += 256) {
    unsigned kp = __hip_atomic_load(&mp_key[i], __ATOMIC_RELAXED, __HIP_MEMORY_SCOPE_AGENT);
    unsigned kn = __hip_atomic_load(&mn_key[i], __ATOMIC_RELAXED, __HIP_MEMORY_SCOPE_AGENT);
    float ce = __hip_atomic_load(&ce_row[i], __ATOMIC_RELAXED, __HIP_MEMORY_SCOPE_AGENT);
    float ap = dec_key(kp), an = dec_key(kn);
    s += fmaxf(0.5f + ap - an, 0.f) + fmaxf(0.8f - ap, 0.f) +
         fmaxf(an - 0.4f, 0.f) + ce;
  }
#pragma unroll
  for (int sh = 1; sh < 64; sh <<= 1) s += __shfl_xor(s, sh, 64);
  if (lane == 0) red[wv] = s;
  __syncthreads();
  if (threadIdx.x == 0)
    out[0] = (red[0] + red[1] + red[2] + red[3]) * (1.0f / N_ROWS);
}

extern "C" void kernel_launch(void* const* d_in, const int* in_sizes, int n_in,
                              void* d_out, int out_size, void* d_ws, size_t ws_size,
                              hipStream_t stream) {
  const float* x   = (const float*)d_in[0];
  const int*   tgt = (const int*)d_in[1];
  char* ws = (char*)d_ws;

  unsigned short* xb     = (unsigned short*)ws;                          // 2 MB bf16 normalized
  unsigned*       mp_key = (unsigned*)(ws + (2u << 20));                 // 64 KB
  unsigned*       mn_key = (unsigned*)(ws + (2u << 20) + (64u << 10));   // 64 KB
  float*          ce_row = (float*)(ws + (2u << 20) + (128u << 10));     // 64 KB
  unsigned*       done   = (unsigned*)(ws + (2u << 20) + (192u << 10));  // 4 B (poison base)
  unsigned*       pz     = done + 1;                                     // reserved, never written
  float*          out    = (float*)d_out;

  prep_kernel<<<N_ROWS / 4, 256, 0, stream>>>(x, tgt, xb, ce_row, mp_key, mn_key);
  mine_kernel<<<(N_ROWS / 128) * 16, 256, 0, stream>>>(xb, tgt, mp_key, mn_key,
                                                       ce_row, pz, done, out);
}

// Round 16
// 162.892 us; speedup vs baseline: 1.3851x; 1.3851x over previous
//
#include <hip/hip_runtime.h>

// TripletAngularMarginLoss: bs=16384, d=64 (== number of classes)
// out = mean(relu(0.5 + ap - an)) + mean(relu(0.8-ap)) + mean(relu(an-0.4)) + CE
// ap[i] = min_{t[j]==t[i]} cos(x_i,x_j), an[i] = max_{t[j]!=t[i]} cos(x_i,x_j)
//
// R15 ledger: finalize-fold perturbed regalloc into per-phase spill (177us).
// Reverted to the 3-kernel R7 structure (best verified: 156 total / 106 mine).
// New theory: arch-VGPR count is always ~half the budget (56/128, 40/85,
// 32/64) -> compiler splits the unified file and holds MFMA accs (+mp/mn) in
// AGPRs; mining pays v_accvgpr round-trips on every op (~100 extra VALU/jc =
// the entire unexplained VALUBusy). R16: inline-asm MFMA with "v" constraints
// pins accumulators to arch VGPRs. Hazard nops included (compiler can't see
// asm semantics): s_nop 1 pre-chain, s_nop 7+2 post-chain before VALU reads.

#define N_ROWS 16384
#define N_DIM 64

typedef __attribute__((ext_vector_type(8))) short bf16x8;
typedef __attribute__((ext_vector_type(4))) float f32x4;

__device__ inline unsigned short f2bf(float f) {
  unsigned u = __float_as_uint(f);
  unsigned r = u + 0x7fffu + ((u >> 16) & 1u);   // round-to-nearest-even
  return (unsigned short)(r >> 16);
}

// order-preserving float->uint encoding for atomicMin/atomicMax
__device__ inline unsigned enc_key(float f) {
  unsigned u = __float_as_uint(f);
  return (u & 0x80000000u) ? ~u : (u | 0x80000000u);
}
__device__ inline float dec_key(unsigned k) {
  unsigned u = (k & 0x80000000u) ? (k ^ 0x80000000u) : ~k;
  return __uint_as_float(u);
}

// async global->LDS DMA, 16B per lane, dest = lds_base + lane*16 (linear)
__device__ inline void g2lds16(const void* g, void* l) {
  __builtin_amdgcn_global_load_lds(
      (const __attribute__((address_space(1))) void*)g,
      (__attribute__((address_space(3))) void*)l, 16, 0, 0);
}

// ---------------- Kernel A: normalize rows, emit bf16 copy, per-row CE -------
// No max-pass (verified correct R15): |xn|<=1 -> exp in [0.37,2.72], sum<=174.
__global__ void prep_kernel(const float* __restrict__ x, const int* __restrict__ tgt,
                            unsigned short* __restrict__ xb, float* __restrict__ ce_row,
                            unsigned* __restrict__ mp_key, unsigned* __restrict__ mn_key,
                            float* __restrict__ out) {
  const int row  = blockIdx.x * 4 + (threadIdx.x >> 6);
  const int lane = threadIdx.x & 63;
  float v  = x[row * N_DIM + lane];
  float ss = v * v;
#pragma unroll
  for (int s = 1; s < 64; s <<= 1) ss += __shfl_xor(ss, s, 64);
  float xn = v * rsqrtf(ss);
  xb[row * N_DIM + lane] = f2bf(xn);

  float e  = __expf(xn);
  float se = e;
#pragma unroll
  for (int s = 1; s < 64; s <<= 1) se += __shfl_xor(se, s, 64);
  float lse = __logf(se);
  int   t   = tgt[row];                 // wave-uniform
  float xt  = __shfl(xn, t, 64);
  if (lane == 0) {
    ce_row[row] = lse - xt;
    mp_key[row] = 0xFFFFFFFFu;          // +inf key for atomicMin
    mn_key[row] = 0u;                   // -inf key for atomicMax
  }
  if (blockIdx.x == 0 && threadIdx.x == 0) out[0] = 0.f;
}

// ---------------- Kernel B: MFMA similarity tiles + hard mining --------------
// R7 structure verbatim (grid 2048, 4-tile phases, dbuf, XOR-swizzle,
// unroll-1 j4, one __syncthreads per phase). ONLY change: MFMAs are inline
// asm with "v" constraints so acc lives in ARCH VGPRs (no accvgpr traffic
// in the mining ops that read it).
__global__ __launch_bounds__(256, 8)
void mine_kernel(const unsigned short* __restrict__ xb, const int* __restrict__ tgt,
                 unsigned* __restrict__ mp_key, unsigned* __restrict__ mn_key) {
  __shared__ unsigned short Bt[2][4][1024];   // 2 bufs x 4 tiles x 2KB, swizzled
  __shared__ unsigned short tjl[N_ROWS / 16]; // 2KB: targets of this j-range

  const int lane    = threadIdx.x & 63;
  const int wv      = threadIdx.x >> 6;
  const int iblk    = blockIdx.x >> 4;
  const int jspl    = blockIdx.x & 15;
  const int rowbase = iblk * 128 + wv * 32;
  const int m = lane & 15, q = lane >> 4;
  const int jbase = jspl * (N_ROWS / 16);

  // A fragments: lane holds row (rowbase+tr*16+m), k = q*8..q*8+7 (+32 for ks=1)
  bf16x8 a[2][2];
#pragma unroll
  for (int tr = 0; tr < 2; ++tr) {
    const unsigned short* p = xb + (rowbase + tr * 16 + m) * N_DIM + q * 8;
    a[tr][0] = *(const bf16x8*)(p);
    a[tr][1] = *(const bf16x8*)(p + 32);
  }
  int ti[2][4];
#pragma unroll
  for (int tr = 0; tr < 2; ++tr)
#pragma unroll
    for (int r = 0; r < 4; ++r)
      ti[tr][r] = tgt[rowbase + tr * 16 + q * 4 + r];

  float mp[8], mn[8];
#pragma unroll
  for (int k = 0; k < 8; ++k) { mp[k] = __builtin_inff(); mn[k] = -__builtin_inff(); }

  for (int k = threadIdx.x; k < N_ROWS / 16; k += 256)
    tjl[k] = (unsigned short)tgt[jbase + k];

  // Staging (inverse-swizzled global source, linear LDS dest):
  const unsigned short* src0 =
      xb + (jbase + (lane >> 3)) * N_DIM + (((lane & 7) ^ ((lane >> 3) & 7)) * 8);

#define STAGE(P_, BUF)                                                           \
  do {                                                                           \
    const unsigned short* s_ = src0 + ((P_) * 64 + wv * 16) * N_DIM;             \
    g2lds16(s_,             (unsigned short*)&Bt[(BUF)][wv][0] + lane * 8);      \
    g2lds16(s_ + 8 * N_DIM, (unsigned short*)&Bt[(BUF)][wv][0] + 512 + lane * 8);\
  } while (0)

  STAGE(0, 0);
  __syncthreads();

  // swizzled fragment-read byte offsets (constant per lane)
  const int roff0 = m * 128 + ((q * 16) ^ ((m & 7) << 4));
  const int roff1 = m * 128 + (((64) + q * 16) ^ ((m & 7) << 4));

  for (int ph = 0; ph < 16; ++ph) {
    const int pb = ph & 1;
    if (ph < 15) STAGE(ph + 1, pb ^ 1);
#pragma unroll 1
    for (int j4 = 0; j4 < 4; ++j4) {
      const int jc = ph * 4 + j4;
      const char* bb = (const char*)&Bt[pb][j4][0];
      const bf16x8 cb0 = *(const bf16x8*)(bb + roff0);
      const bf16x8 cb1 = *(const bf16x8*)(bb + roff1);
      const int    ctj = tjl[jc * 16 + m];

#pragma unroll
      for (int tr = 0; tr < 2; ++tr) {
        f32x4 acc = {0.f, 0.f, 0.f, 0.f};
        // s_nop 1: VALU zero-init -> MFMA srcC hazard (2 wait states).
        asm("s_nop 1\n\t"
            "v_mfma_f32_16x16x32_bf16 %0, %1, %2, %0"
            : "+v"(acc) : "v"(a[tr][0]), "v"(cb0));
        // chained same-shape accumulate: back-to-back legal; trailing nops
        // cover MFMA-dst -> VALU-read (11 wait states) for the mining ops.
        asm("v_mfma_f32_16x16x32_bf16 %0, %1, %2, %0\n\t"
            "s_nop 7\n\ts_nop 2"
            : "+v"(acc) : "v"(a[tr][1]), "v"(cb1));
#pragma unroll
        for (int r = 0; r < 4; ++r) {
          const bool  pos = (ctj == ti[tr][r]);
          const float d   = acc[r];
          const int   k   = tr * 4 + r;
          mp[k] = fminf(mp[k], pos ? d : __builtin_inff());
          mn[k] = fmaxf(mn[k], pos ? -__builtin_inff() : d);
        }
      }
    }
    __syncthreads();   // one vmcnt-drain + barrier per 4-tile phase
  }
#undef STAGE

  // reduce across the 16 lanes (m = 0..15) inside each q-group
#pragma unroll
  for (int s = 1; s < 16; s <<= 1) {
#pragma unroll
    for (int k = 0; k < 8; ++k) {
      mp[k] = fminf(mp[k], __shfl_xor(mp[k], s, 64));
      mn[k] = fmaxf(mn[k], __shfl_xor(mn[k], s, 64));
    }
  }
  if (m == 0) {
#pragma unroll
    for (int tr = 0; tr < 2; ++tr)
#pragma unroll
      for (int r = 0; r < 4; ++r) {
        const int row = rowbase + tr * 16 + q * 4 + r;
        atomicMin(&mp_key[row], enc_key(mp[tr * 4 + r]));
        atomicMax(&mn_key[row], enc_key(mn[tr * 4 + r]));
      }
  }
}

// ---------------- Kernel C: final reduction (8 blocks, float atomicAdd) ------
__global__ void finalize_kernel(const unsigned* __restrict__ mp_key, const unsigned* __restrict__ mn_key,
                                const float* __restrict__ ce_row, float* __restrict__ out) {
  __shared__ float red[16];
  float s = 0.f;
#pragma unroll
  for (int it = 0; it < 2; ++it) {
    const int r = it * 8192 + blockIdx.x * 1024 + threadIdx.x;
    float ap = dec_key(mp_key[r]);
    float an = dec_key(mn_key[r]);
    s += fmaxf(0.5f + ap - an, 0.f) + fmaxf(0.8f - ap, 0.f) +
         fmaxf(an - 0.4f, 0.f) + ce_row[r];
  }
#pragma unroll
  for (int sh = 1; sh < 64; sh <<= 1) s += __shfl_xor(s, sh, 64);
  const int wv = threadIdx.x >> 6;
  if ((threadIdx.x & 63) == 0) red[wv] = s;
  __syncthreads();
  if (threadIdx.x == 0) {
    float t = 0.f;
#pragma unroll
    for (int w = 0; w < 16; ++w) t += red[w];
    atomicAdd(out, t * (1.0f / N_ROWS));
  }
}

extern "C" void kernel_launch(void* const* d_in, const int* in_sizes, int n_in,
                              void* d_out, int out_size, void* d_ws, size_t ws_size,
                              hipStream_t stream) {
  const float* x   = (const float*)d_in[0];
  const int*   tgt = (const int*)d_in[1];
  char* ws = (char*)d_ws;

  unsigned short* xb     = (unsigned short*)ws;                          // 2 MB bf16 normalized
  unsigned*       mp_key = (unsigned*)(ws + (2u << 20));                 // 64 KB
  unsigned*       mn_key = (unsigned*)(ws + (2u << 20) + (64u << 10));   // 64 KB
  float*          ce_row = (float*)(ws + (2u << 20) + (128u << 10));     // 64 KB
  float*          out    = (float*)d_out;

  prep_kernel<<<N_ROWS / 4, 256, 0, stream>>>(x, tgt, xb, ce_row, mp_key, mn_key, out);
  mine_kernel<<<(N_ROWS / 128) * 16, 256, 0, stream>>>(xb, tgt, mp_key, mn_key);
  finalize_kernel<<<8, 1024, 0, stream>>>(mp_key, mn_key, ce_row, out);
}

// Round 17
// 139.103 us; speedup vs baseline: 1.6220x; 1.1710x over previous
//
#include <hip/hip_runtime.h>

// TripletAngularMarginLoss: bs=16384, d=64 (== number of classes)
// out = mean(relu(0.5 + ap - an)) + mean(relu(0.8-ap)) + mean(relu(an-0.4)) + CE
// ap[i] = min_{t[j]==t[i]} cos(x_i,x_j), an[i] = max_{t[j]!=t[i]} cos(x_i,x_j)
//
// R17: CLASS-ENCODING AUGMENTATION. K: 64->128. A-side rows append +16*e_cls,
// B-side rows append -16*e_cls => MFMA computes D = cos - 256*[same class].
// Mining = min/max only (2 VALU/elem, was 5 + ti/ctj machinery). Recovery:
// ap = mp+256 (diagonal guarantees a positive), an = mn (negatives always
// exist: 64 classes over 16384 rows). 16/-16 exact bf16; 256 exact fp32;
// recovery error <= ulp(256) = 3e-5 << tolerated bf16 error.

#define N_ROWS 16384
#define KDIM 128

typedef __attribute__((ext_vector_type(8))) short bf16x8;
typedef __attribute__((ext_vector_type(4))) float f32x4;

__device__ inline unsigned short f2bf(float f) {
  unsigned u = __float_as_uint(f);
  unsigned r = u + 0x7fffu + ((u >> 16) & 1u);   // round-to-nearest-even
  return (unsigned short)(r >> 16);
}

// order-preserving float->uint encoding for atomicMin/atomicMax
__device__ inline unsigned enc_key(float f) {
  unsigned u = __float_as_uint(f);
  return (u & 0x80000000u) ? ~u : (u | 0x80000000u);
}
__device__ inline float dec_key(unsigned k) {
  unsigned u = (k & 0x80000000u) ? (k ^ 0x80000000u) : ~k;
  return __uint_as_float(u);
}

// async global->LDS DMA, 16B per lane, dest = lds_base + lane*16 (linear)
__device__ inline void g2lds16(const void* g, void* l) {
  __builtin_amdgcn_global_load_lds(
      (const __attribute__((address_space(1))) void*)g,
      (__attribute__((address_space(3))) void*)l, 16, 0, 0);
}

// ---------------- Kernel A: normalize, augmented bf16 copies, per-row CE -----
// xbA[row] = [bf16(xn), +16*onehot(t)] ; xbB[row] = [bf16(xn), -16*onehot(t)]
// CE: no max-pass (verified R15): |xn|<=1 -> exp in [0.37,2.72], sum<=174.
__global__ void prep_kernel(const float* __restrict__ x, const int* __restrict__ tgt,
                            unsigned short* __restrict__ xbA, unsigned short* __restrict__ xbB,
                            float* __restrict__ ce_row,
                            unsigned* __restrict__ mp_key, unsigned* __restrict__ mn_key,
                            float* __restrict__ out) {
  const int row  = blockIdx.x * 4 + (threadIdx.x >> 6);
  const int lane = threadIdx.x & 63;
  float v  = x[row * 64 + lane];
  float ss = v * v;
#pragma unroll
  for (int s = 1; s < 64; s <<= 1) ss += __shfl_xor(ss, s, 64);
  float xn = v * rsqrtf(ss);
  int   t  = tgt[row];                  // wave-uniform
  const unsigned short b = f2bf(xn);
  xbA[row * KDIM + lane] = b;
  xbB[row * KDIM + lane] = b;
  xbA[row * KDIM + 64 + lane] = (lane == t) ? (unsigned short)0x4180u : (unsigned short)0u; // +16
  xbB[row * KDIM + 64 + lane] = (lane == t) ? (unsigned short)0xC180u : (unsigned short)0u; // -16

  float e  = __expf(xn);
  float se = e;
#pragma unroll
  for (int s = 1; s < 64; s <<= 1) se += __shfl_xor(se, s, 64);
  float lse = __logf(se);
  float xt  = __shfl(xn, t, 64);
  if (lane == 0) {
    ce_row[row] = lse - xt;
    mp_key[row] = 0xFFFFFFFFu;          // +inf key for atomicMin
    mn_key[row] = 0u;                   // -inf key for atomicMax
  }
  if (blockIdx.x == 0 && threadIdx.x == 0) out[0] = 0.f;
}

// ---------------- Kernel B: augmented MFMA similarity + min/max mining -------
// grid = 128 i-blocks * 16 j-splits = 2048 blocks of 256 threads (4 waves) =
// 4 blocks/CU (launch_bounds(256,4): 128-reg budget for ~82 live regs).
// Tile = 16 cols x 128 dims (4KB); 4-tile phases, double-buffered; all 4
// waves cooperate per tile (256 lanes x 16B = 4KB = one g2lds16 each).
// Swizzle: tile[col][slot s] holds dim-granule s^col (16B granules);
// read addr = m*256 + ((ks*64+q*16) ^ (m<<4)) -> bank-exact 8-round minimum.
__global__ __launch_bounds__(256, 4)
void mine_kernel(const unsigned short* __restrict__ xbA, const unsigned short* __restrict__ xbB,
                 unsigned* __restrict__ mp_key, unsigned* __restrict__ mn_key) {
  __shared__ unsigned short Bt[2][4][2048];   // 2 bufs x 4 tiles x 4KB, swizzled

  const int lane    = threadIdx.x & 63;
  const int wv      = threadIdx.x >> 6;
  const int iblk    = blockIdx.x >> 4;
  const int jspl    = blockIdx.x & 15;
  const int rowbase = iblk * 128 + wv * 32;
  const int m = lane & 15, q = lane >> 4;
  const int jbase = jspl * (N_ROWS / 16);

  // A fragments (augmented): lane holds row (rowbase+tr*16+m), K-slice ks:
  // dims ks*32 + q*8 .. +7
  bf16x8 a[2][4];
#pragma unroll
  for (int tr = 0; tr < 2; ++tr) {
    const unsigned short* p = xbA + (rowbase + tr * 16 + m) * KDIM + q * 8;
#pragma unroll
    for (int ks = 0; ks < 4; ++ks) a[tr][ks] = *(const bf16x8*)(p + ks * 32);
  }

  float mp[8], mn[8];
#pragma unroll
  for (int k = 0; k < 8; ++k) { mp[k] = __builtin_inff(); mn[k] = -__builtin_inff(); }

  // staging: thread covers col ct of each tile, granule gsel = (lane&15)^ct
  const int ct   = wv * 4 + (lane >> 4);
  const int gsel = (lane & 15) ^ ct;
  const unsigned short* srcb = xbB + (jbase + ct) * KDIM + gsel * 8;

#define STAGE(P_, BUF)                                                            \
  do {                                                                            \
    _Pragma("unroll")                                                             \
    for (int ti = 0; ti < 4; ++ti)                                                \
      g2lds16(srcb + ((P_) * 64 + ti * 16) * KDIM,                                \
              (unsigned short*)&Bt[(BUF)][ti][0] + wv * 512 + lane * 8);          \
  } while (0)

  STAGE(0, 0);
  __syncthreads();

  // swizzled fragment-read byte offsets (constant per lane), one per K-slice
  int roff[4];
#pragma unroll
  for (int ks = 0; ks < 4; ++ks)
    roff[ks] = m * 256 + ((ks * 64 + q * 16) ^ (m << 4));

  for (int ph = 0; ph < 16; ++ph) {
    const int pb = ph & 1;
    if (ph < 15) STAGE(ph + 1, pb ^ 1);
#pragma unroll 1
    for (int j4 = 0; j4 < 4; ++j4) {
      const char* tb = (const char*)&Bt[pb][j4][0];
      const bf16x8 cb0 = *(const bf16x8*)(tb + roff[0]);
      const bf16x8 cb1 = *(const bf16x8*)(tb + roff[1]);
      const bf16x8 cb2 = *(const bf16x8*)(tb + roff[2]);
      const bf16x8 cb3 = *(const bf16x8*)(tb + roff[3]);

#pragma unroll
      for (int tr = 0; tr < 2; ++tr) {
        f32x4 acc = {0.f, 0.f, 0.f, 0.f};
        acc = __builtin_amdgcn_mfma_f32_16x16x32_bf16(a[tr][0], cb0, acc, 0, 0, 0);
        acc = __builtin_amdgcn_mfma_f32_16x16x32_bf16(a[tr][1], cb1, acc, 0, 0, 0);
        acc = __builtin_amdgcn_mfma_f32_16x16x32_bf16(a[tr][2], cb2, acc, 0, 0, 0);
        acc = __builtin_amdgcn_mfma_f32_16x16x32_bf16(a[tr][3], cb3, acc, 0, 0, 0);
        // D = cos - 256*pos: mining is pure min/max (2 VALU per element)
#pragma unroll
        for (int r = 0; r < 4; ++r) {
          const int k = tr * 4 + r;
          mp[k] = fminf(mp[k], acc[r]);
          mn[k] = fmaxf(mn[k], acc[r]);
        }
      }
    }
    __syncthreads();   // one vmcnt-drain + barrier per 4-tile phase
  }
#undef STAGE

  // reduce across the 16 lanes (m = 0..15) inside each q-group
#pragma unroll
  for (int s = 1; s < 16; s <<= 1) {
#pragma unroll
    for (int k = 0; k < 8; ++k) {
      mp[k] = fminf(mp[k], __shfl_xor(mp[k], s, 64));
      mn[k] = fmaxf(mn[k], __shfl_xor(mn[k], s, 64));
    }
  }
  if (m == 0) {
#pragma unroll
    for (int tr = 0; tr < 2; ++tr)
#pragma unroll
      for (int r = 0; r < 4; ++r) {
        const int row = rowbase + tr * 16 + q * 4 + r;
        atomicMin(&mp_key[row], enc_key(mp[tr * 4 + r]));
        atomicMax(&mn_key[row], enc_key(mn[tr * 4 + r]));
      }
  }
}

// ---------------- Kernel C: final reduction (8 blocks, float atomicAdd) ------
__global__ void finalize_kernel(const unsigned* __restrict__ mp_key, const unsigned* __restrict__ mn_key,
                                const float* __restrict__ ce_row, float* __restrict__ out) {
  __shared__ float red[16];
  float s = 0.f;
#pragma unroll
  for (int it = 0; it < 2; ++it) {
    const int r = it * 8192 + blockIdx.x * 1024 + threadIdx.x;
    float ap = dec_key(mp_key[r]) + 256.f;   // undo the -256 class offset
    float an = dec_key(mn_key[r]);           // negatives unaffected
    s += fmaxf(0.5f + ap - an, 0.f) + fmaxf(0.8f - ap, 0.f) +
         fmaxf(an - 0.4f, 0.f) + ce_row[r];
  }
#pragma unroll
  for (int sh = 1; sh < 64; sh <<= 1) s += __shfl_xor(s, sh, 64);
  const int wv = threadIdx.x >> 6;
  if ((threadIdx.x & 63) == 0) red[wv] = s;
  __syncthreads();
  if (threadIdx.x == 0) {
    float t = 0.f;
#pragma unroll
    for (int w = 0; w < 16; ++w) t += red[w];
    atomicAdd(out, t * (1.0f / N_ROWS));
  }
}

extern "C" void kernel_launch(void* const* d_in, const int* in_sizes, int n_in,
                              void* d_out, int out_size, void* d_ws, size_t ws_size,
                              hipStream_t stream) {
  const float* x   = (const float*)d_in[0];
  const int*   tgt = (const int*)d_in[1];
  char* ws = (char*)d_ws;

  unsigned short* xbA    = (unsigned short*)ws;                          // 4 MB augmented (A)
  unsigned short* xbB    = (unsigned short*)(ws + (4u << 20));           // 4 MB augmented (B)
  unsigned*       mp_key = (unsigned*)(ws + (8u << 20));                 // 64 KB
  unsigned*       mn_key = (unsigned*)(ws + (8u << 20) + (64u << 10));   // 64 KB
  float*          ce_row = (float*)(ws + (8u << 20) + (128u << 10));     // 64 KB
  float*          out    = (float*)d_out;

  prep_kernel<<<N_ROWS / 4, 256, 0, stream>>>(x, tgt, xbA, xbB, ce_row, mp_key, mn_key, out);
  mine_kernel<<<(N_ROWS / 128) * 16, 256, 0, stream>>>(xbA, xbB, mp_key, mn_key);
  finalize_kernel<<<8, 1024, 0, stream>>>(mp_key, mn_key, ce_row, out);
}